// Round 5
// baseline (77.632 us; speedup 1.0000x reference)
//
#include <hip/hip_runtime.h>
#include <cstddef>
#include <cstdint>

typedef __attribute__((ext_vector_type(8))) _Float16 f16x8;
typedef __attribute__((ext_vector_type(4))) float f32x4;

constexpr int S = 128;
constexpr int H = 64;
constexpr int A = 8;
constexpr float GAMMA = 0.98f;
constexpr float EPS_CLIP = 0.1f;

__device__ __forceinline__ float swishf(float x) {
    return x * __builtin_amdgcn_rcpf(1.0f + __expf(-x));
}
__device__ __forceinline__ f32x4 mfmaf(f16x8 a, f16x8 b, f32x4 c) {
    return __builtin_amdgcn_mfma_f32_16x16x32_f16(a, b, c, 0, 0, 0);
}

// One fused forward per 256 rows: 512-thread block, 8 waves.
// Waves 0-3 (role 0): s-MLP for rows [blk*256 + w*64, +64) -> v_s, softmax,
//   pi_a kept in registers.
// Waves 4-7 (role 1): s'-MLP for the SAME rows -> v_sp dropped into LDS.
// One barrier joins them; s-waves then run the whole per-row PPO epilogue
// in-register and write out[t] (sans huber mean) + block huber partial.
// vs r1's failed fusion: weight-frag sharing per wave is preserved (2 row-
// tiles per double-tile), softmax only on 4/8 waves, occupancy config is
// r4's proven (512,2) (VGPR 64, no spills). Eliminates ppo_epi (launch +
// 12 MB ws round-trip). Launches 3 -> 2.
// A-frag (16x32 f16): lane l holds A[l&15][(l>>4)*8 + j].
// B-frag: lane l holds B[(l>>4)*8 + j][l&15].  C/D: col=lane&15, row=(lane>>4)*4+reg.
__global__ __launch_bounds__(512, 2) void ppo_fwd(
    const float* __restrict__ s, const float* __restrict__ sp,
    const float* __restrict__ r, const float* __restrict__ done,
    const float* __restrict__ prob_a, const int* __restrict__ aidx,
    const float* __restrict__ W1, const float* __restrict__ b1,
    const float* __restrict__ W2, const float* __restrict__ b2,
    const float* __restrict__ Wa, const float* __restrict__ ba,
    const float* __restrict__ Wc, const float* __restrict__ bc,
    float* __restrict__ out, float* __restrict__ partial)
{
    __shared__ f16x8 sW1[16][64];                        // 16 KB
    __shared__ f16x8 sW2[8][64];                         //  8 KB
    __shared__ f16x8 sWh[2][64];                         //  2 KB
    __shared__ __align__(16) _Float16 hbuf[8][16 * 72];  // 18 KB
    __shared__ float hs[4][16 * 11];                     //  2.75 KB (s-waves only)
    __shared__ float vspb[256];                          //  1 KB (v_sp exchange)
    __shared__ float wred[8];

    const int tid = threadIdx.x;
    const int wid = tid >> 6, l = tid & 63, g = l >> 4, n15 = l & 15;
    const int role = wid >> 2;          // 0: s-wave, 1: s'-wave
    const int w4 = wid & 3;
    const int base = blockIdx.x * 256 + w4 * 64;   // this wave's 64 rows
    const float* __restrict__ x = role ? sp : s;

    // ---- early per-row scalar loads (s-waves, hidden under staging) ----
    float rr4[4], dm4[4], pa4[4];
    int act4[4] = {0, 0, 0, 0};
    if (role == 0 && l < 16) {
        #pragma unroll
        for (int c = 0; c < 4; ++c) {
            const int t = base + c * 16 + l;
            rr4[c] = r[t]; dm4[c] = done[t]; pa4[c] = prob_a[t]; act4[c] = aidx[t];
        }
    }

    // ---- pack weight fragments (single fp16 term) ----
    for (int idx = tid; idx < 16 * 64; idx += 512) {
        int f = idx >> 6, ll = idx & 63;
        int nt = f >> 2, kk = f & 3;
        int gg = ll >> 4, col = nt * 16 + (ll & 15);
        f16x8 v;
        #pragma unroll
        for (int j = 0; j < 8; ++j)
            v[j] = (_Float16)W1[(kk * 32 + gg * 8 + j) * H + col];
        sW1[f][ll] = v;
    }
    for (int idx = tid; idx < 8 * 64; idx += 512) {
        int f = idx >> 6, ll = idx & 63;
        int nt = f >> 1, kk = f & 1;
        int gg = ll >> 4, col = nt * 16 + (ll & 15);
        f16x8 v;
        #pragma unroll
        for (int j = 0; j < 8; ++j)
            v[j] = (_Float16)W2[(kk * 32 + gg * 8 + j) * H + col];
        sW2[f][ll] = v;
    }
    for (int idx = tid; idx < 2 * 64; idx += 512) {
        int kk = idx >> 6, ll = idx & 63;
        int gg = ll >> 4, q = ll & 15;
        f16x8 v;
        #pragma unroll
        for (int j = 0; j < 8; ++j) {
            int k = kk * 32 + gg * 8 + j;
            v[j] = (_Float16)((q == 0) ? Wc[k] : ((q <= 8) ? Wa[k * A + (q - 1)] : 0.0f));
        }
        sWh[kk][ll] = v;
    }
    __syncthreads();

    _Float16* hb = hbuf[wid];
    float* hsw = hs[w4];   // only dereferenced by role-0 waves

    float b1r[4], b2r[4];
    #pragma unroll
    for (int nt = 0; nt < 4; ++nt) { b1r[nt] = b1[nt * 16 + n15]; b2r[nt] = b2[nt * 16 + n15]; }
    const float bhr = (n15 == 0) ? bc[0] : ((n15 <= 8) ? ba[n15 - 1] : 0.0f);

    float vsr[4], piar[4];

    #pragma unroll
    for (int mt2 = 0; mt2 < 2; ++mt2) {
        const int t0 = base + mt2 * 32;

        // ---- load x rows, convert to fp16 A-frags ----
        f16x8 ax[2][4];   // [tile][kk]
        #pragma unroll
        for (int tile = 0; tile < 2; ++tile) {
            const float* row = x + (size_t)(t0 + tile * 16 + n15) * S + g * 8;
            #pragma unroll
            for (int kk = 0; kk < 4; ++kk) {
                float4 v0 = *reinterpret_cast<const float4*>(row + kk * 32);
                float4 v1 = *reinterpret_cast<const float4*>(row + kk * 32 + 4);
                f16x8 a;
                a[0] = (_Float16)v0.x; a[1] = (_Float16)v0.y;
                a[2] = (_Float16)v0.z; a[3] = (_Float16)v0.w;
                a[4] = (_Float16)v1.x; a[5] = (_Float16)v1.y;
                a[6] = (_Float16)v1.z; a[7] = (_Float16)v1.w;
                ax[tile][kk] = a;
            }
        }

        // ---- layer 1: [16x128]@[128x64], both tiles share each W-frag read ----
        f32x4 acc[2][4];
        #pragma unroll
        for (int tile = 0; tile < 2; ++tile)
            #pragma unroll
            for (int nt = 0; nt < 4; ++nt)
                acc[tile][nt] = (f32x4){b1r[nt], b1r[nt], b1r[nt], b1r[nt]};
        #pragma unroll
        for (int nt = 0; nt < 4; ++nt)
            #pragma unroll
            for (int kk = 0; kk < 4; ++kk) {
                f16x8 bw = sW1[nt * 4 + kk][l];
                acc[0][nt] = mfmaf(ax[0][kk], bw, acc[0][nt]);
                acc[1][nt] = mfmaf(ax[1][kk], bw, acc[1][nt]);
            }

        // ---- swish + LDS transpose (C layout -> A layout), per tile ----
        f16x8 a2[2][2];
        #pragma unroll
        for (int tile = 0; tile < 2; ++tile) {
            #pragma unroll
            for (int nt = 0; nt < 4; ++nt)
                #pragma unroll
                for (int rj = 0; rj < 4; ++rj)
                    hb[(g * 4 + rj) * 72 + nt * 16 + n15] =
                        (_Float16)swishf(acc[tile][nt][rj]);
            #pragma unroll
            for (int kk = 0; kk < 2; ++kk)
                a2[tile][kk] = *reinterpret_cast<f16x8*>(&hb[n15 * 72 + kk * 32 + g * 8]);
        }

        // ---- layer 2: [16x64]@[64x64] ----
        f32x4 acc2[2][4];
        #pragma unroll
        for (int tile = 0; tile < 2; ++tile)
            #pragma unroll
            for (int nt = 0; nt < 4; ++nt)
                acc2[tile][nt] = (f32x4){b2r[nt], b2r[nt], b2r[nt], b2r[nt]};
        #pragma unroll
        for (int nt = 0; nt < 4; ++nt)
            #pragma unroll
            for (int kk = 0; kk < 2; ++kk) {
                f16x8 bw = sW2[nt * 2 + kk][l];
                acc2[0][nt] = mfmaf(a2[0][kk], bw, acc2[0][nt]);
                acc2[1][nt] = mfmaf(a2[1][kk], bw, acc2[1][nt]);
            }

        // ---- transpose again -> head A-frags ----
        f16x8 a3[2][2];
        #pragma unroll
        for (int tile = 0; tile < 2; ++tile) {
            #pragma unroll
            for (int nt = 0; nt < 4; ++nt)
                #pragma unroll
                for (int rj = 0; rj < 4; ++rj)
                    hb[(g * 4 + rj) * 72 + nt * 16 + n15] =
                        (_Float16)swishf(acc2[tile][nt][rj]);
            #pragma unroll
            for (int kk = 0; kk < 2; ++kk)
                a3[tile][kk] = *reinterpret_cast<f16x8*>(&hb[n15 * 72 + kk * 32 + g * 8]);
        }

        // ---- head: [16x64]@[64x16] (col0=v, col1..8=logits) ----
        f32x4 ah[2] = {(f32x4){bhr, bhr, bhr, bhr}, (f32x4){bhr, bhr, bhr, bhr}};
        #pragma unroll
        for (int kk = 0; kk < 2; ++kk) {
            f16x8 bw = sWh[kk][l];
            ah[0] = mfmaf(a3[0][kk], bw, ah[0]);
            ah[1] = mfmaf(a3[1][kk], bw, ah[1]);
        }

        if (role) {
            // v_sp -> LDS; col 0 = lanes with n15==0; rows g*4+rj
            #pragma unroll
            for (int tile = 0; tile < 2; ++tile)
                if (n15 == 0) {
                    #pragma unroll
                    for (int rj = 0; rj < 4; ++rj)
                        vspb[w4 * 64 + mt2 * 32 + tile * 16 + g * 4 + rj] = ah[tile][rj];
                }
        } else {
            // stash v + logits, softmax on lanes 0..15; keep vs/pia in regs
            #pragma unroll
            for (int tile = 0; tile < 2; ++tile) {
                if (n15 <= 8) {
                    #pragma unroll
                    for (int rj = 0; rj < 4; ++rj)
                        hsw[(g * 4 + rj) * 11 + n15] = ah[tile][rj];
                }
                if (l < 16) {
                    float vs = hsw[l * 11 + 0];
                    float lgq[A];
                    float m = -1e30f;
                    #pragma unroll
                    for (int q = 0; q < A; ++q) {
                        lgq[q] = hsw[l * 11 + 1 + q];
                        m = fmaxf(m, lgq[q]);
                    }
                    float den = 0.f, num = 0.f;
                    #pragma unroll
                    for (int q = 0; q < A; ++q) {
                        float e = __expf(lgq[q] - m);
                        den += e;
                        num = (q == act4[mt2 * 2 + tile]) ? e : num;
                    }
                    vsr[mt2 * 2 + tile]  = vs;
                    piar[mt2 * 2 + tile] = num / den;
                }
            }
        }
    }

    __syncthreads();   // v_sp ready

    // ---- per-row PPO epilogue on s-waves, lanes 0..15 ----
    float hacc = 0.f;
    if (role == 0 && l < 16) {
        #pragma unroll
        for (int c = 0; c < 4; ++c) {
            const int t = base + c * 16 + l;
            float vs  = vsr[c];
            float pia = piar[c];
            float vsp = vspb[w4 * 64 + c * 16 + l];
            float ratio = pia / pa4[c];

            float td  = fmaf(GAMMA * dm4[c], vsp, rr4[c]);
            float dlt = rr4[c] + GAMMA * vsp - vs;
            float s1 = ratio * dlt;
            float rcl = fminf(fmaxf(ratio, 1.0f - EPS_CLIP), 1.0f + EPS_CLIP);
            float s2 = rcl * dlt;
            out[t] = -fminf(s1, s2);      // huber mean added by ppo_finish

            float err = td - vs;
            float ae = fabsf(err);
            hacc += (ae <= 1.0f) ? (0.5f * err * err) : (ae - 0.5f);
        }
    }

    // ---- block huber partial: wave shuffle-reduce, then 8-way LDS ----
    #pragma unroll
    for (int off = 32; off > 0; off >>= 1)
        hacc += __shfl_down(hacc, off, 64);
    if (l == 0) wred[wid] = hacc;
    __syncthreads();
    if (tid == 0) {
        float v = 0.f;
        #pragma unroll
        for (int i = 0; i < 8; ++i) v += wred[i];
        partial[blockIdx.x] = v;
    }
}

// Every block reduces the (L2-resident) partial array to the huber mean, then
// adds it to its own slice of out.
__global__ __launch_bounds__(256) void ppo_finish(
    const float* __restrict__ partial, int nparts, float invT,
    float4* __restrict__ out4, int n4)
{
    __shared__ float sred[256];
    const int tid = threadIdx.x;
    float v = 0.f;
    for (int i = tid; i < nparts; i += 256) v += partial[i];
    sred[tid] = v;
    __syncthreads();
    #pragma unroll
    for (int off = 128; off > 0; off >>= 1) {
        if (tid < off) sred[tid] += sred[tid + off];
        __syncthreads();
    }
    const float m = sred[0] * invT;
    const int i = blockIdx.x * 256 + tid;
    if (i < n4) {
        float4 o = out4[i];
        o.x += m; o.y += m; o.z += m; o.w += m;
        out4[i] = o;
    }
}

extern "C" void kernel_launch(void* const* d_in, const int* in_sizes, int n_in,
                              void* d_out, int out_size, void* d_ws, size_t ws_size,
                              hipStream_t stream)
{
    const float* s      = (const float*)d_in[0];
    const float* sp     = (const float*)d_in[1];
    const float* r      = (const float*)d_in[2];
    const float* done   = (const float*)d_in[3];
    const float* prob_a = (const float*)d_in[4];
    const int*   a      = (const int*)d_in[5];
    const float* W1     = (const float*)d_in[6];
    const float* b1     = (const float*)d_in[7];
    const float* W2     = (const float*)d_in[8];
    const float* b2     = (const float*)d_in[9];
    const float* Wa     = (const float*)d_in[10];
    const float* ba     = (const float*)d_in[11];
    const float* Wc     = (const float*)d_in[12];
    const float* bc     = (const float*)d_in[13];

    float* out = (float*)d_out;
    float* partial = (float*)d_ws;

    const int Ttot = in_sizes[0] / S;              // 262144
    const int nbf  = Ttot / 256;                   // 1024 blocks, 256 rows each

    ppo_fwd<<<nbf, 512, 0, stream>>>(s, sp, r, done, prob_a, a,
                                     W1, b1, W2, b2, Wa, ba, Wc, bc,
                                     out, partial);

    const int n4 = Ttot / 4;
    ppo_finish<<<(n4 + 255) / 256, 256, 0, stream>>>(partial, nbf,
                                                     1.0f / (float)Ttot,
                                                     (float4*)out, n4);
}